// Round 6
// baseline (431.969 us; speedup 1.0000x reference)
//
#include <hip/hip_runtime.h>
#include <cstdint>
#include <cstddef>

// ---------------------------------------------------------------------------
// SeparableCritic: out = l2norm(MLP(x)) @ l2norm(MLP(y))^T
// N=8192, D=64, H=512, L=128. fp32 I/O, bf16 MFMA internals.
// Round 8: encoder-fused v2. Same structure as R7 (one kernel x/y -> zn,
// per-wave 16 rows end-to-end, zero barriers, swizzled per-wave LDS scratch)
// but with OUTER LOOPS NOT UNROLLED (#pragma unroll 1): straight-line body
// shrinks ~8x (prior version: ~704 fully-unrolled MFMAs -> suspected
// compile/regalloc pathology as the container-killer; small-bodied kernels
// passed in R0/R4 on the same harness).
// Launch structure (5): 3x transpose_cast, encoder_fused, gemm_nt_k128.
// ---------------------------------------------------------------------------

typedef unsigned short u16;
typedef __attribute__((ext_vector_type(8))) short bf16x8;  // 8 bf16 = 4 VGPRs
typedef __attribute__((ext_vector_type(4))) float f32x4;   // MFMA C/D
typedef __attribute__((ext_vector_type(4))) u16  u16x4;    // packed bf16 x4

__device__ __forceinline__ u16 f_to_bf16_bits(float f) {
    union { float f; uint32_t u; } v; v.f = f;
    uint32_t lsb = (v.u >> 16) & 1u;
    return (u16)((v.u + 0x7fffu + lsb) >> 16);   // round-to-nearest-even
}

// in[R][C] fp32 -> out[C][R] bf16 (weight transpose+cast; tiny, L2-served).
__global__ __launch_bounds__(256) void transpose_cast_kernel(
    const float* __restrict__ in, u16* __restrict__ out, int R, int C)
{
    int idx = blockIdx.x * 256 + threadIdx.x;
    if (idx < R * C) {
        int r = idx / C, c = idx - r * C;
        out[c * R + r] = f_to_bf16_bits(in[r * C + c]);
    }
}

// ---------------------------------------------------------------------------
// Fused encoder: zn[row] = l2norm(relu(relu(in[row]W1+b1)W2+b2)W3+b3).
// Grid 256 x 256thr. Wave w of block b owns rows b*64+w*16 .. +15.
// MFMA (swapped ops): mfma(wf, af), wf = WT[cb*16+mi][k..8], af =
// act[rows, k..8]; D reg r at lane(mi,quad) = [out col cb*16+quad*4+r][row mi].
// LDS: per-wave [16][512] bf16 scratch, XOR-swizzled (chunk ^ (mi&7)<<4)
// so layer-input frag reads (16 lanes @ 1024B stride) are conflict-free.
// h1 then h2 reuse the same scratch; next layer's 16 input frags are
// hoisted to VGPRs before overwrite. No __syncthreads anywhere.
// Outer loops intentionally NOT unrolled (code-size / compile risk).
// ---------------------------------------------------------------------------
__global__ __launch_bounds__(256) void encoder_fused_kernel(
    const float* __restrict__ X, const float* __restrict__ Y,
    const u16* __restrict__ W1T, const u16* __restrict__ W2T,
    const u16* __restrict__ W3T,
    const float* __restrict__ b1, const float* __restrict__ b2,
    const float* __restrict__ b3,
    u16* __restrict__ ZN)
{
    __shared__ u16 hbuf[4 * 16 * 512];   // 64 KB total, 16 KB per wave
    const int lane = threadIdx.x & 63;
    const int wave = threadIdx.x >> 6;
    const int mi   = lane & 15;
    const int quad = lane >> 4;
    const int grow = blockIdx.x * 64 + wave * 16 + mi;   // 0..16383
    const float* srow = (grow < 8192) ? (X + (size_t)grow * 64)
                                      : (Y + (size_t)(grow - 8192) * 64);
    char* hw = (char*)(hbuf + wave * 16 * 512);  // this wave's [16][512]
    const int rbase = mi * 1024;                 // lane's LDS row base (bytes)
    const int swz   = (mi & 7) << 4;             // XOR on 16B-chunk index

    // ---- input frags: x[row][0..63] fp32 -> bf16, 2 k-steps ----
    bf16x8 xf[2];
    #pragma unroll
    for (int ks = 0; ks < 2; ++ks) {
        const float* p = srow + ks * 32 + quad * 8;
        float4 f0 = *reinterpret_cast<const float4*>(p);
        float4 f1 = *reinterpret_cast<const float4*>(p + 4);
        union { u16 u[8]; bf16x8 v; } cv;
        cv.u[0] = f_to_bf16_bits(f0.x); cv.u[1] = f_to_bf16_bits(f0.y);
        cv.u[2] = f_to_bf16_bits(f0.z); cv.u[3] = f_to_bf16_bits(f0.w);
        cv.u[4] = f_to_bf16_bits(f1.x); cv.u[5] = f_to_bf16_bits(f1.y);
        cv.u[6] = f_to_bf16_bits(f1.z); cv.u[7] = f_to_bf16_bits(f1.w);
        xf[ks] = cv.v;
    }

    // ---- layer 1: h1[16][512] = relu(x @ W1 + b1) ----
    #pragma unroll 1
    for (int cbg = 0; cbg < 8; ++cbg) {          // 4 col-blocks per iter (ILP)
        f32x4 a[4];
        #pragma unroll
        for (int j = 0; j < 4; ++j) a[j] = f32x4{0.f, 0.f, 0.f, 0.f};
        #pragma unroll
        for (int ks = 0; ks < 2; ++ks) {
            #pragma unroll
            for (int j = 0; j < 4; ++j) {
                const int cb = cbg * 4 + j;
                bf16x8 wf = *reinterpret_cast<const bf16x8*>(
                    W1T + (size_t)(cb * 16 + mi) * 64 + ks * 32 + quad * 8);
                a[j] = __builtin_amdgcn_mfma_f32_16x16x32_bf16(wf, xf[ks], a[j], 0, 0, 0);
            }
        }
        #pragma unroll
        for (int j = 0; j < 4; ++j) {
            const int cb = cbg * 4 + j;
            const float* bp = b1 + cb * 16 + quad * 4;
            u16x4 pk;
            #pragma unroll
            for (int r = 0; r < 4; ++r)
                pk[r] = f_to_bf16_bits(fmaxf(a[j][r] + bp[r], 0.f));
            *reinterpret_cast<u16x4*>(hw + rbase + ((cb * 32 + quad * 8) ^ swz)) = pk;
        }
    }

    // ---- hoist h1 frags, then layer 2: h2 = relu(h1 @ W2 + b2) ----
    bf16x8 hf[16];
    #pragma unroll
    for (int ks = 0; ks < 16; ++ks)
        hf[ks] = *reinterpret_cast<const bf16x8*>(
            hw + rbase + ((ks * 64 + quad * 16) ^ swz));
    #pragma unroll 1
    for (int cbg = 0; cbg < 8; ++cbg) {
        f32x4 a[4];
        #pragma unroll
        for (int j = 0; j < 4; ++j) a[j] = f32x4{0.f, 0.f, 0.f, 0.f};
        #pragma unroll 1
        for (int ks = 0; ks < 16; ++ks) {
            #pragma unroll
            for (int j = 0; j < 4; ++j) {
                const int cb = cbg * 4 + j;
                bf16x8 wf = *reinterpret_cast<const bf16x8*>(
                    W2T + (size_t)(cb * 16 + mi) * 512 + ks * 32 + quad * 8);
                a[j] = __builtin_amdgcn_mfma_f32_16x16x32_bf16(wf, hf[ks], a[j], 0, 0, 0);
            }
        }
        #pragma unroll
        for (int j = 0; j < 4; ++j) {
            const int cb = cbg * 4 + j;
            const float* bp = b2 + cb * 16 + quad * 4;
            u16x4 pk;
            #pragma unroll
            for (int r = 0; r < 4; ++r)
                pk[r] = f_to_bf16_bits(fmaxf(a[j][r] + bp[r], 0.f));
            *reinterpret_cast<u16x4*>(hw + rbase + ((cb * 32 + quad * 8) ^ swz)) = pk;
        }
    }

    // ---- hoist h2 frags (reuse hf), layer 3 + bias + l2norm ----
    #pragma unroll
    for (int ks = 0; ks < 16; ++ks)
        hf[ks] = *reinterpret_cast<const bf16x8*>(
            hw + rbase + ((ks * 64 + quad * 16) ^ swz));
    f32x4 zv[8];
    #pragma unroll
    for (int cb = 0; cb < 8; ++cb) zv[cb] = f32x4{0.f, 0.f, 0.f, 0.f};
    #pragma unroll 1
    for (int ks = 0; ks < 16; ++ks) {
        #pragma unroll
        for (int cb = 0; cb < 8; ++cb) {
            bf16x8 wf = *reinterpret_cast<const bf16x8*>(
                W3T + (size_t)(cb * 16 + mi) * 512 + ks * 32 + quad * 8);
            zv[cb] = __builtin_amdgcn_mfma_f32_16x16x32_bf16(wf, hf[ks], zv[cb], 0, 0, 0);
        }
    }
    float s = 0.f;
    #pragma unroll
    for (int cb = 0; cb < 8; ++cb) {
        const float* bp = b3 + cb * 16 + quad * 4;
        #pragma unroll
        for (int r = 0; r < 4; ++r) {
            zv[cb][r] += bp[r];
            s += zv[cb][r] * zv[cb][r];
        }
    }
    s += __shfl_xor(s, 16, 64);
    s += __shfl_xor(s, 32, 64);
    const float inv = 1.0f / fmaxf(sqrtf(s), 1e-12f);
    u16* zrow = ZN + (size_t)grow * 128;
    #pragma unroll
    for (int cb = 0; cb < 8; ++cb) {
        u16x4 pk;
        #pragma unroll
        for (int r = 0; r < 4; ++r) pk[r] = f_to_bf16_bits(zv[cb][r] * inv);
        *reinterpret_cast<u16x4*>(zrow + cb * 16 + quad * 4) = pk;
    }
}

// Final GEMM: out[r][c] = znx[r] . zny[c], K=128, fp32 out. Barrier-free,
// LDS-free: zn is 4 MB -> L2-resident; fragments load straight from global.
// Swapped operands so lane's f32x4 acc = 4 consecutive cols of one out row
// -> global_store_dwordx4 epilogue. (Unchanged; R4 bisect-verified PASS.)
__global__ __launch_bounds__(256) void gemm_nt_k128_kernel(
    const u16* __restrict__ ZX, const u16* __restrict__ ZY,
    float* __restrict__ out)
{
    const int lane = threadIdx.x & 63;
    const int wave = threadIdx.x >> 6;
    const int mi   = lane & 15;
    const int quad = lane >> 4;
    const int wr = wave >> 1, wc = wave & 1;
    const int rb = blockIdx.y * 128 + wr * 64;   // out rows (znx)
    const int cb = blockIdx.x * 128 + wc * 64;   // out cols (zny)

    f32x4 acc[4][4];   // [ci][rj]
    #pragma unroll
    for (int ci = 0; ci < 4; ++ci)
        #pragma unroll
        for (int rj = 0; rj < 4; ++rj)
            acc[ci][rj] = f32x4{0.f, 0.f, 0.f, 0.f};

    const u16* xbase = ZX + (size_t)(rb + mi) * 128 + quad * 8;
    const u16* ybase = ZY + (size_t)(cb + mi) * 128 + quad * 8;

    #pragma unroll
    for (int ks = 0; ks < 4; ++ks) {
        bf16x8 yf[4], xf[4];
        #pragma unroll
        for (int t = 0; t < 4; ++t) {
            yf[t] = *reinterpret_cast<const bf16x8*>(ybase + (size_t)t * 16 * 128 + ks * 32);
            xf[t] = *reinterpret_cast<const bf16x8*>(xbase + (size_t)t * 16 * 128 + ks * 32);
        }
        #pragma unroll
        for (int ci = 0; ci < 4; ++ci)
            #pragma unroll
            for (int rj = 0; rj < 4; ++rj)
                acc[ci][rj] = __builtin_amdgcn_mfma_f32_16x16x32_bf16(
                    yf[ci], xf[rj], acc[ci][rj], 0, 0, 0);
    }

    #pragma unroll
    for (int rj = 0; rj < 4; ++rj) {
        float* orow = out + (size_t)(rb + rj * 16 + mi) * 8192 + cb + quad * 4;
        #pragma unroll
        for (int ci = 0; ci < 4; ++ci)
            *reinterpret_cast<f32x4*>(orow + ci * 16) = acc[ci][rj];
    }
}

extern "C" void kernel_launch(void* const* d_in, const int* in_sizes, int n_in,
                              void* d_out, int out_size, void* d_ws, size_t ws_size,
                              hipStream_t stream)
{
    const float* x  = (const float*)d_in[0];   // [8192, 64]
    const float* y  = (const float*)d_in[1];   // [8192, 64]
    const float* W1 = (const float*)d_in[2];   // [64, 512]
    const float* b1 = (const float*)d_in[3];   // [512]
    const float* W2 = (const float*)d_in[4];   // [512, 512]
    const float* b2 = (const float*)d_in[5];   // [512]
    const float* W3 = (const float*)d_in[6];   // [512, 128]
    const float* b3 = (const float*)d_in[7];   // [128]
    float* out = (float*)d_out;                // [8192, 8192] fp32

    // Workspace: weight transposes + zn only (~4.7 MB).
    u16* ws  = (u16*)d_ws;
    u16* W1T = ws;                              // [512][64]
    u16* W2T = W1T + 512 * 64;                  // [512][512]
    u16* W3T = W2T + 512 * 512;                 // [128][512]
    u16* zn  = W3T + 128 * 512;                 // [16384][128]

    dim3 blk(256);

    // Transpose+cast weights to [N][K] bf16.
    transpose_cast_kernel<<<128,  blk, 0, stream>>>(W1, W1T, 64, 512);
    transpose_cast_kernel<<<1024, blk, 0, stream>>>(W2, W2T, 512, 512);
    transpose_cast_kernel<<<256,  blk, 0, stream>>>(W3, W3T, 512, 128);

    // Whole encoder (cast + 3 layers + l2norm) in one launch.
    encoder_fused_kernel<<<256, blk, 0, stream>>>(
        x, y, W1T, W2T, W3T, b1, b2, b3, zn);

    // out = zx @ zy^T (TEMP=1.0).
    gemm_nt_k128_kernel<<<dim3(64, 64), blk, 0, stream>>>(
        zn, zn + (size_t)8192 * 128, out);
}

// Round 7
// 376.906 us; speedup vs baseline: 1.1461x; 1.1461x over previous
//
#include <hip/hip_runtime.h>
#include <cstdint>
#include <cstddef>

// ---------------------------------------------------------------------------
// SeparableCritic: out = l2norm(MLP(x)) @ l2norm(MLP(y))^T
// N=8192, D=64, H=512, L=128. fp32 I/O, bf16 MFMA internals.
// Round 9: revert fused encoder (R8: 432 us, SLOWER than chain by 51 us —
// 1 wave/SIMD L2-latency-bound weight streaming). Back to R4-passing config
// (380.8 us) with three surgical cuts:
//   * casts merged 2->1 launch; weight transposes merged 3->1 launch
//   * gemm3+l2norm fused kernel (extracted from the VERIFIED layer-3 block
//     of R8's encoder; unroll-1 loop, modest body): 256 blocks (old gemm3
//     ran 128 = half GPU idle), removes fp32 z round-trip. -2 launches.
//   * gemm1/gemm2 (LDS template) and gemm_nt unchanged, byte-identical.
// Launches: 10 -> 6. Lesson kept: no mega-unrolled bodies (container-killer).
// ---------------------------------------------------------------------------

typedef unsigned short u16;
typedef __attribute__((ext_vector_type(8))) short bf16x8;  // 8 bf16 = 4 VGPRs
typedef __attribute__((ext_vector_type(4))) float f32x4;   // MFMA C/D
typedef __attribute__((ext_vector_type(4))) u16  u16x4;    // packed bf16 x4

__device__ __forceinline__ u16 f_to_bf16_bits(float f) {
    union { float f; uint32_t u; } v; v.f = f;
    uint32_t lsb = (v.u >> 16) & 1u;
    return (u16)((v.u + 0x7fffu + lsb) >> 16);   // round-to-nearest-even
}

// Both input casts in one launch: xy[0..524287] <- X, xy[524288..] <- Y.
__global__ __launch_bounds__(256) void cast_inputs_kernel(
    const float* __restrict__ X, const float* __restrict__ Y,
    u16* __restrict__ xy)
{
    int i = blockIdx.x * 256 + threadIdx.x;   // < 1048576
    float v = (i < 524288) ? X[i] : Y[i - 524288];
    xy[i] = f_to_bf16_bits(v);
}

// All three weight transpose+casts in one launch (range-dispatched).
// W1[64][512]->W1T[512][64]; W2[512][512]->W2T; W3[512][128]->W3T[128][512].
__global__ __launch_bounds__(256) void transpose_weights_kernel(
    const float* __restrict__ W1, const float* __restrict__ W2,
    const float* __restrict__ W3,
    u16* __restrict__ W1T, u16* __restrict__ W2T, u16* __restrict__ W3T)
{
    int idx = blockIdx.x * 256 + threadIdx.x;   // < 360448
    if (idx < 32768) {                           // W1: R=64, C=512
        int r = idx >> 9, c = idx & 511;
        W1T[c * 64 + r] = f_to_bf16_bits(W1[idx]);
    } else if (idx < 294912) {                   // W2: R=512, C=512
        int k = idx - 32768;
        int r = k >> 9, c = k & 511;
        W2T[c * 512 + r] = f_to_bf16_bits(W2[k]);
    } else if (idx < 360448) {                   // W3: R=512, C=128
        int k = idx - 294912;
        int r = k >> 7, c = k & 127;
        W3T[c * 512 + r] = f_to_bf16_bits(W3[k]);
    }
}

// C[M,N] = act(A[M,K] @ BT[N,K]^T + bias). A,BT row-major bf16.
// Block: 256 thr = 4 waves (2x2), 128x128 tile, each wave 64x64 (4x4 MFMA).
// m97-style global_load_lds staging into fragment-ordered LDS. (R4-verified.)
template<bool RELU>
__global__ __launch_bounds__(256) void gemm_lds_kernel(
    const u16* __restrict__ A, const u16* __restrict__ BT,
    const float* __restrict__ bias,
    u16* __restrict__ Cb,
    int M, int N, int K)
{
    __shared__ u16 lds[16 * 512];   // 16 KB
    const int lane = threadIdx.x & 63;
    const int wave = threadIdx.x >> 6;
    const int wm = wave >> 1, wn = wave & 1;
    const int m_base = blockIdx.y * 128;
    const int n_base = blockIdx.x * 128;
    const int mi   = lane & 15;   // frag row / C col within 16-tile
    const int quad = lane >> 4;   // frag k-subrange; C row group

    f32x4 acc[4][4];
    #pragma unroll
    for (int i = 0; i < 4; ++i)
        #pragma unroll
        for (int j = 0; j < 4; ++j)
            acc[i][j] = f32x4{0.f, 0.f, 0.f, 0.f};

    const u16* src[4];
    #pragma unroll
    for (int s = 0; s < 4; ++s) {
        const int t = wave * 4 + s;
        if (t < 8)
            src[s] = A + (size_t)(m_base + t * 16 + mi) * K + quad * 8;
        else
            src[s] = BT + (size_t)(n_base + (t - 8) * 16 + mi) * K + quad * 8;
    }
    u16* dst_base = &lds[wave * 4 * 512];   // wave-uniform

    for (int k0 = 0; k0 < K; k0 += 32) {
        #pragma unroll
        for (int s = 0; s < 4; ++s) {
            __builtin_amdgcn_global_load_lds(
                (const __attribute__((address_space(1))) void*)(src[s] + k0),
                (__attribute__((address_space(3))) void*)(dst_base + s * 512),
                16, 0, 0);
        }
        __syncthreads();

        bf16x8 af[4], bfr[4];
        #pragma unroll
        for (int i = 0; i < 4; ++i)
            af[i] = *reinterpret_cast<const bf16x8*>(&lds[(wm * 4 + i) * 512 + lane * 8]);
        #pragma unroll
        for (int j = 0; j < 4; ++j)
            bfr[j] = *reinterpret_cast<const bf16x8*>(&lds[(8 + wn * 4 + j) * 512 + lane * 8]);

        #pragma unroll
        for (int i = 0; i < 4; ++i)
            #pragma unroll
            for (int j = 0; j < 4; ++j)
                acc[i][j] = __builtin_amdgcn_mfma_f32_16x16x32_bf16(
                    af[i], bfr[j], acc[i][j], 0, 0, 0);

        __syncthreads();
    }

    // Epilogue: C/D layout col = lane&15, row = quad*4 + reg [m89-verified].
    const int wm_base = m_base + wm * 64;
    const int wn_base = n_base + wn * 64;
    #pragma unroll
    for (int j = 0; j < 4; ++j) {
        const int col = wn_base + j * 16 + mi;
        float bv = bias[col];
        #pragma unroll
        for (int i = 0; i < 4; ++i) {
            const int row0 = wm_base + i * 16 + quad * 4;
            #pragma unroll
            for (int r = 0; r < 4; ++r) {
                float v = acc[i][j][r] + bv;
                if (RELU) v = fmaxf(v, 0.f);
                Cb[(size_t)(row0 + r) * N + col] = f_to_bf16_bits(v);
            }
        }
    }
}

// Fused GEMM3 + bias + L2-normalize (extracted from R8's PASSED encoder
// layer-3 block; same frag math / loop shape, h2 read from global).
//   zn[row] = l2norm(h2[row] @ W3 + b3), h2:[16384][512], W3T:[128][512].
// Wave owns 16 rows; lane(mi,quad) holds row grow=base+mi, k-slice quad*8.
// mfma(wf, hf): D[quad*4+r -> out col][mi -> row]; row sumsq reduced over
// lanes {mi, mi+16, mi+32, mi+48} via shfl_xor(16), shfl_xor(32).
// Grid 256 x 256thr = full GPU. No barriers. Modest body (unroll 1 on ks).
__global__ __launch_bounds__(256) void gemm3_l2norm_kernel(
    const u16* __restrict__ H2, const u16* __restrict__ W3T,
    const float* __restrict__ b3, u16* __restrict__ ZN)
{
    const int lane = threadIdx.x & 63;
    const int wave = threadIdx.x >> 6;
    const int mi   = lane & 15;
    const int quad = lane >> 4;
    const int grow = blockIdx.x * 64 + wave * 16 + mi;   // 0..16383

    // Hoist this lane's 16 h2 fragments (row grow, 16B each).
    bf16x8 hf[16];
    const u16* hbase = H2 + (size_t)grow * 512 + quad * 8;
    #pragma unroll
    for (int ks = 0; ks < 16; ++ks)
        hf[ks] = *reinterpret_cast<const bf16x8*>(hbase + ks * 32);

    f32x4 zv[8];
    #pragma unroll
    for (int cb = 0; cb < 8; ++cb) zv[cb] = f32x4{0.f, 0.f, 0.f, 0.f};

    const u16* wbase = W3T + (size_t)mi * 512 + quad * 8;
    #pragma unroll 1
    for (int ks = 0; ks < 16; ++ks) {
        #pragma unroll
        for (int cb = 0; cb < 8; ++cb) {
            bf16x8 wf = *reinterpret_cast<const bf16x8*>(
                wbase + (size_t)cb * 16 * 512 + ks * 32);
            zv[cb] = __builtin_amdgcn_mfma_f32_16x16x32_bf16(wf, hf[ks], zv[cb], 0, 0, 0);
        }
    }

    // bias (scalar loads) + sumsq; all lane values belong to row grow.
    float s = 0.f;
    #pragma unroll
    for (int cb = 0; cb < 8; ++cb) {
        const float* bp = b3 + cb * 16 + quad * 4;
        #pragma unroll
        for (int r = 0; r < 4; ++r) {
            zv[cb][r] += bp[r];
            s += zv[cb][r] * zv[cb][r];
        }
    }
    s += __shfl_xor(s, 16, 64);
    s += __shfl_xor(s, 32, 64);
    const float inv = 1.0f / fmaxf(sqrtf(s), 1e-12f);

    u16* zrow = ZN + (size_t)grow * 128;
    #pragma unroll
    for (int cb = 0; cb < 8; ++cb) {
        u16x4 pk;
        #pragma unroll
        for (int r = 0; r < 4; ++r) pk[r] = f_to_bf16_bits(zv[cb][r] * inv);
        *reinterpret_cast<u16x4*>(zrow + cb * 16 + quad * 4) = pk;
    }
}

// Final GEMM: out[r][c] = znx[r] . zny[c], K=128, fp32 out. Barrier-free,
// LDS-free: zn is 4 MB -> L2-resident; fragments load straight from global.
// Swapped operands so lane's f32x4 acc = 4 consecutive cols of one out row
// -> global_store_dwordx4 epilogue. (Unchanged; R4 bisect-verified PASS.)
__global__ __launch_bounds__(256) void gemm_nt_k128_kernel(
    const u16* __restrict__ ZX, const u16* __restrict__ ZY,
    float* __restrict__ out)
{
    const int lane = threadIdx.x & 63;
    const int wave = threadIdx.x >> 6;
    const int mi   = lane & 15;
    const int quad = lane >> 4;
    const int wr = wave >> 1, wc = wave & 1;
    const int rb = blockIdx.y * 128 + wr * 64;   // out rows (znx)
    const int cb = blockIdx.x * 128 + wc * 64;   // out cols (zny)

    f32x4 acc[4][4];   // [ci][rj]
    #pragma unroll
    for (int ci = 0; ci < 4; ++ci)
        #pragma unroll
        for (int rj = 0; rj < 4; ++rj)
            acc[ci][rj] = f32x4{0.f, 0.f, 0.f, 0.f};

    const u16* xbase = ZX + (size_t)(rb + mi) * 128 + quad * 8;
    const u16* ybase = ZY + (size_t)(cb + mi) * 128 + quad * 8;

    #pragma unroll
    for (int ks = 0; ks < 4; ++ks) {
        bf16x8 yf[4], xf[4];
        #pragma unroll
        for (int t = 0; t < 4; ++t) {
            yf[t] = *reinterpret_cast<const bf16x8*>(ybase + (size_t)t * 16 * 128 + ks * 32);
            xf[t] = *reinterpret_cast<const bf16x8*>(xbase + (size_t)t * 16 * 128 + ks * 32);
        }
        #pragma unroll
        for (int ci = 0; ci < 4; ++ci)
            #pragma unroll
            for (int rj = 0; rj < 4; ++rj)
                acc[ci][rj] = __builtin_amdgcn_mfma_f32_16x16x32_bf16(
                    yf[ci], xf[rj], acc[ci][rj], 0, 0, 0);
    }

    #pragma unroll
    for (int rj = 0; rj < 4; ++rj) {
        float* orow = out + (size_t)(rb + rj * 16 + mi) * 8192 + cb + quad * 4;
        #pragma unroll
        for (int ci = 0; ci < 4; ++ci)
            *reinterpret_cast<f32x4*>(orow + ci * 16) = acc[ci][rj];
    }
}

extern "C" void kernel_launch(void* const* d_in, const int* in_sizes, int n_in,
                              void* d_out, int out_size, void* d_ws, size_t ws_size,
                              hipStream_t stream)
{
    const float* x  = (const float*)d_in[0];   // [8192, 64]
    const float* y  = (const float*)d_in[1];   // [8192, 64]
    const float* W1 = (const float*)d_in[2];   // [64, 512]
    const float* b1 = (const float*)d_in[3];   // [512]
    const float* W2 = (const float*)d_in[4];   // [512, 512]
    const float* b2 = (const float*)d_in[5];   // [512]
    const float* W3 = (const float*)d_in[6];   // [512, 128]
    const float* b3 = (const float*)d_in[7];   // [128]
    float* out = (float*)d_out;                // [8192, 8192] fp32

    // Workspace (all bf16 as u16). ~40 MB.
    u16* ws  = (u16*)d_ws;
    u16* xy  = ws;                              // [16384][64]
    u16* W1T = xy  + (size_t)16384 * 64;        // [512][64]
    u16* W2T = W1T + 512 * 64;                  // [512][512]
    u16* W3T = W2T + 512 * 512;                 // [128][512]
    u16* h1  = W3T + 128 * 512;                 // [16384][512]
    u16* h2  = h1  + (size_t)16384 * 512;       // [16384][512]
    u16* zn  = h2  + (size_t)16384 * 512;       // [16384][128]

    dim3 blk(256);

    // 1. Both input casts, one launch.
    cast_inputs_kernel<<<4096, blk, 0, stream>>>(x, y, xy);

    // 2. All weight transposes, one launch (360448 elems).
    transpose_weights_kernel<<<1408, blk, 0, stream>>>(
        W1, W2, W3, W1T, W2T, W3T);

    // 3-4. Encoder layers 1-2, batched M=16384.
    gemm_lds_kernel<true><<<dim3(4, 128), blk, 0, stream>>>(
        xy, W1T, b1, h1, 16384, 512, 64);
    gemm_lds_kernel<true><<<dim3(4, 128), blk, 0, stream>>>(
        h1, W2T, b2, h2, 16384, 512, 512);

    // 5. Layer 3 + bias + l2norm, full GPU, no z round-trip.
    gemm3_l2norm_kernel<<<256, blk, 0, stream>>>(h2, W3T, b3, zn);

    // 6. out = zx @ zy^T (TEMP=1.0).
    gemm_nt_k128_kernel<<<dim3(64, 64), blk, 0, stream>>>(
        zn, zn + (size_t)8192 * 128, out);
}